// Round 1
// baseline (830.446 us; speedup 1.0000x reference)
//
#include <hip/hip_runtime.h>
#include <hip/hip_bf16.h>

// Problem constants
// B=16, C=64, H=56, W=56
// conv1: x[16,64,56,56] * w1[128,64,7,7] (dil=2, pad=6) -> k1[16,128,56,56]
// conv2: k1 * w2[49,128,1,1] -> softmax over 49 -> attn[16,49,56,56]
// out[F] = sum_k x[b,c,h+2p-6,w+2q-6] * attn_flat[(F>>6)*49 + k],  F in [B,C,H,W] row-major

#define HW 3136            // 56*56
#define NPIX 50176         // 16*3136
#define K1_ELEMS 6422528   // 16*128*3136
#define OUT_ELEMS 3211264  // 16*64*3136

// ---------------- conv1: 7x7 dilated-2, 64->128 ----------------
// grid (7, 8, 16) = (h_tile, oc_group, batch); block 256 = 64 cols x 4 row-slots
// each thread: pixels (h0+rr, col) and (h0+rr+4, col), 16 output channels
__global__ __launch_bounds__(256) void conv1_kernel(
    const float* __restrict__ x, const float* __restrict__ w1,
    const float* __restrict__ b1, float* __restrict__ k1)
{
    __shared__ float xs[20 * 68];  // rows h0-6..h0+13, cols -6..61

    const int h0  = blockIdx.x * 8;
    const int oc0 = blockIdx.y * 16;
    const int b   = blockIdx.z;
    const int tid = threadIdx.x;
    const int col = tid & 63;
    const int rr  = tid >> 6;

    float acc0[16], acc1[16];
#pragma unroll
    for (int o = 0; o < 16; ++o) { acc0[o] = 0.f; acc1[o] = 0.f; }

    const float* xb = x + (size_t)b * 64 * HW;

    for (int ic = 0; ic < 64; ++ic) {
        __syncthreads();  // protect xs from previous iteration's readers
        // stage x tile (zero-padded)
        for (int i = tid; i < 20 * 68; i += 256) {
            int r = i / 68, cc = i - r * 68;
            int hh = h0 - 6 + r, ww = cc - 6;
            float v = 0.f;
            if (hh >= 0 && hh < 56 && ww >= 0 && ww < 56)
                v = xb[ic * HW + hh * 56 + ww];
            xs[i] = v;
        }
        __syncthreads();

        if (col < 56) {
            const float* wp = w1 + ((size_t)oc0 * 64 + ic) * 49;  // stride per-oc: 64*49
            for (int p = 0; p < 7; ++p) {
                const float* wpp = wp + p * 7;
                const float* xr0 = xs + (rr + 2 * p) * 68 + col;
                const float* xr1 = xs + (rr + 4 + 2 * p) * 68 + col;
#pragma unroll
                for (int q = 0; q < 7; ++q) {
                    float xv0 = xr0[2 * q];
                    float xv1 = xr1[2 * q];
#pragma unroll
                    for (int o = 0; o < 16; ++o) {
                        float wv = wpp[(size_t)o * 3136 + q];  // block-uniform -> s_load
                        acc0[o] = fmaf(xv0, wv, acc0[o]);
                        acc1[o] = fmaf(xv1, wv, acc1[o]);
                    }
                }
            }
        }
    }

    if (col < 56) {
#pragma unroll
        for (int o = 0; o < 16; ++o) {
            float bias = b1[oc0 + o];
            size_t base = ((size_t)b * 128 + oc0 + o) * HW;
            k1[base + (h0 + rr) * 56 + col]     = acc0[o] + bias;
            k1[base + (h0 + rr + 4) * 56 + col] = acc1[o] + bias;
        }
    }
}

// ---------------- conv2 (1x1, 128->49) + softmax over 49 ----------------
// grid 196, block 256: one thread per pixel (b, s)
__global__ __launch_bounds__(256) void conv2_softmax_kernel(
    const float* __restrict__ k1, const float* __restrict__ w2,
    const float* __restrict__ b2, float* __restrict__ attn)
{
    __shared__ float w2s[49 * 128];
    for (int i = threadIdx.x; i < 49 * 128; i += 256) w2s[i] = w2[i];
    __syncthreads();

    int gpix = blockIdx.x * 256 + threadIdx.x;  // 0..50175
    int b = gpix / HW;
    int s = gpix - b * HW;

    float logit[49];
#pragma unroll
    for (int a = 0; a < 49; ++a) logit[a] = b2[a];

    const float* kp = k1 + (size_t)b * 128 * HW + s;
    for (int m = 0; m < 128; ++m) {
        float v = kp[(size_t)m * HW];
#pragma unroll
        for (int a = 0; a < 49; ++a)
            logit[a] = fmaf(v, w2s[a * 128 + m], logit[a]);
    }

    float mx = logit[0];
#pragma unroll
    for (int a = 1; a < 49; ++a) mx = fmaxf(mx, logit[a]);
    float sum = 0.f;
#pragma unroll
    for (int a = 0; a < 49; ++a) { logit[a] = __expf(logit[a] - mx); sum += logit[a]; }
    float inv = 1.f / sum;

    float* ap = attn + (size_t)b * (49 * HW) + s;
#pragma unroll
    for (int a = 0; a < 49; ++a) ap[(size_t)a * HW] = logit[a] * inv;
}

// ---------------- final grouped einsum ----------------
// out[F] = sum_k x_pad_tap(F,k) * attn_flat[(F>>6)*49 + k]
// grid 12544, block 256; each 64-lane wave shares one g (wave-uniform attn vector)
__global__ __launch_bounds__(256) void gather_kernel(
    const float* __restrict__ x, const float* __restrict__ attn,
    float* __restrict__ out)
{
    int F = blockIdx.x * 256 + threadIdx.x;  // < OUT_ELEMS
    int g = F >> 6;

    int w = F % 56;
    int t = F / 56;
    int h = t % 56;
    t /= 56;  // t = b*64 + c  (plane index into x)

    const float* xp = x + (size_t)t * HW;
    const float* ap = attn + (size_t)g * 49;

    float acc = 0.f;
#pragma unroll
    for (int p = 0; p < 7; ++p) {
        int hh = h + 2 * p - 6;
        bool hok = (hh >= 0) && (hh < 56);
#pragma unroll
        for (int q = 0; q < 7; ++q) {
            int ww = w + 2 * q - 6;
            float a = ap[p * 7 + q];  // wave-uniform
            float xv = 0.f;
            if (hok && ww >= 0 && ww < 56) xv = xp[hh * 56 + ww];
            acc = fmaf(xv, a, acc);
        }
    }
    out[F] = acc;
}

extern "C" void kernel_launch(void* const* d_in, const int* in_sizes, int n_in,
                              void* d_out, int out_size, void* d_ws, size_t ws_size,
                              hipStream_t stream)
{
    const float* x  = (const float*)d_in[0];
    const float* w1 = (const float*)d_in[1];
    const float* b1 = (const float*)d_in[2];
    const float* w2 = (const float*)d_in[3];
    const float* b2 = (const float*)d_in[4];
    float* out = (float*)d_out;

    float* k1   = (float*)d_ws;            // 16*128*3136 floats = 25.7 MB
    float* attn = k1 + K1_ELEMS;           // 16*49*3136 floats  =  9.8 MB

    conv1_kernel<<<dim3(7, 8, 16), 256, 0, stream>>>(x, w1, b1, k1);
    conv2_softmax_kernel<<<196, 256, 0, stream>>>(k1, w2, b2, attn);
    gather_kernel<<<12544, 256, 0, stream>>>(x, attn, out);
}

// Round 2
// 227.006 us; speedup vs baseline: 3.6583x; 3.6583x over previous
//
#include <hip/hip_runtime.h>
#include <hip/hip_bf16.h>

#define HW 3136            // 56*56
#define NPIX 50176         // 16*3136
#define K1_ELEMS 6422528   // 16*128*3136
#define ATTN_ELEMS 2458624 // 16*49*3136
#define OUT_ELEMS 3211264  // 16*64*3136

typedef __attribute__((ext_vector_type(8))) short bf16x8;
typedef __attribute__((ext_vector_type(4))) float f32x4;
typedef __attribute__((ext_vector_type(8))) unsigned short u16x8;

__device__ inline unsigned short f2bf(float v){
    __hip_bfloat16 h = __float2bfloat16(v);
    union { __hip_bfloat16 h; unsigned short u; } cv; cv.h = h; return cv.u;
}
__device__ inline float bf2f(unsigned short u){
    union { unsigned short u; __hip_bfloat16 h; } cv; cv.u = u; return __bfloat162float(cv.h);
}
__device__ inline void gl_lds16(const void* g, void* l){
    __builtin_amdgcn_global_load_lds((const __attribute__((address_space(1))) void*)g,
                                     (__attribute__((address_space(3))) void*)l, 16, 0, 0);
}

// ---------- prep: x[b][ic][h][w] -> xg[(b*4+g)][h][w][32]  (16ic hi ++ 16ic lo, chunk-swizzled) ----------
// physical chunk pc holds logical chunk lj = pc ^ ((w>>1)&3);
// lj 0,1 = hi of ics g*16+{0..7, 8..15}; lj 2,3 = lo of same.
__global__ __launch_bounds__(256) void prep_x(const float* __restrict__ x,
                                              unsigned short* __restrict__ xg)
{
    int pix = blockIdx.x * 256 + threadIdx.x;   // b*3136 + s
    int b = pix / HW;
    int s = pix - b * HW;
    int w = s % 56;
    int sw = (w >> 1) & 3;
    const float* xp = x + (size_t)b * 64 * HW + s;
#pragma unroll
    for (int g = 0; g < 4; ++g) {
        unsigned short* dst = xg + ((size_t)(b * 4 + g) * HW + s) * 32;
#pragma unroll
        for (int pc = 0; pc < 4; ++pc) {
            int lj  = pc ^ sw;
            int icb = g * 16 + (lj & 1) * 8;
            alignas(16) unsigned short tmp[8];
#pragma unroll
            for (int e = 0; e < 8; ++e) {
                float v = xp[(size_t)(icb + e) * HW];
                unsigned short hi = f2bf(v);
                tmp[e] = (lj < 2) ? hi : f2bf(v - bf2f(hi));
            }
            *(u16x8*)(dst + pc * 8) = *(const u16x8*)tmp;
        }
    }
}

// ---------- prep: w1[oc][ic][p][q] -> w1t[tap][oc][ic] bf16 ----------
__global__ __launch_bounds__(256) void prep_w(const float* __restrict__ w1,
                                              unsigned short* __restrict__ w1t)
{
    int t = blockIdx.x * 256 + threadIdx.x;
    if (t >= 49 * 128) return;
    int tap = t / 128, oc = t - tap * 128;
    unsigned short* dst = w1t + (size_t)t * 64;
    for (int ic = 0; ic < 64; ++ic)
        dst[ic] = f2bf(w1[((size_t)oc * 64 + ic) * 49 + tap]);
}

// ---------- conv1 as implicit GEMM on MFMA ----------
// block: 224 flat pixels (4 rows x 56) x 128 ocs; 4 waves = 2M x 2N
// K = 4 ic-groups x 49 taps x K32(16ic x hi/lo)
__global__ __launch_bounds__(256) void conv1_mfma(
    const unsigned short* __restrict__ xg, const unsigned short* __restrict__ w1t,
    const float* __restrict__ b1, float* __restrict__ k1)
{
    __shared__ unsigned short xs[16 * 68 * 32];   // 69632 B

    const int blk  = blockIdx.x;            // 0..223
    const int b    = blk / 14;
    const int h0   = (blk - b * 14) * 4;
    const int tid  = threadIdx.x;
    const int lane = tid & 63;
    const int warp = tid >> 6;
    const int wm   = warp >> 1;             // 0..1 (M half)
    const int oc0  = (warp & 1) * 64;       // N half
    const int li   = lane & 15;
    const int j    = lane >> 4;             // k-chunk 0..3

    int sbase[7], swb[7];
#pragma unroll
    for (int mt = 0; mt < 7; ++mt) {
        int local = wm * 112 + mt * 16 + li;    // 0..223 within block
        int rb = local / 56;                    // 0..3
        int wp = local - rb * 56;
        sbase[mt] = rb * 68 + wp;               // site base (tap p,q adds 136p + 2q)
        swb[mt]   = (wp + 58) >> 1;             // swizzle key base: (ww>>1) == swb+q-32
    }

    f32x4 acc[7][4];
#pragma unroll
    for (int mt = 0; mt < 7; ++mt)
#pragma unroll
        for (int nt = 0; nt < 4; ++nt)
#pragma unroll
            for (int c = 0; c < 4; ++c) acc[mt][nt][c] = 0.f;

    // zero LDS once (halo rows/cols stay zero across all stages)
    {
        f32x4 zv; zv[0] = zv[1] = zv[2] = zv[3] = 0.f;
#pragma unroll 1
        for (int i = tid; i < 16 * 68 * 32 / 8; i += 256)
            *(f32x4*)(xs + (size_t)i * 8) = zv;
    }

    const size_t xgb = (size_t)b * 4 * HW * 32;

#pragma unroll 1
    for (int g = 0; g < 4; ++g) {
        __syncthreads();   // previous readers done (also covers zero-init)
        // stage 16 rows x 56 cols x 64B into LDS (linear dest, swizzle pre-baked in xg)
        for (int rr = warp; rr < 16; rr += 4) {
            int hh = h0 - 6 + rr;
            if (hh >= 0 && hh < 56) {
                const unsigned short* src = xg + xgb + ((size_t)g * HW + hh * 56) * 32;
                char* dstb = (char*)xs + (rr * 68 + 6) * 64;
#pragma unroll
                for (int kk = 0; kk < 4; ++kk) {
                    int idx = kk * 64 + lane;
                    if (idx < 224)
                        gl_lds16(src + idx * 8, dstb + kk * 1024);
                }
            }
        }
        __syncthreads();

        // per-lane B pointers for this ic-group
        const unsigned short* wl[4];
#pragma unroll
        for (int nt = 0; nt < 4; ++nt)
            wl[nt] = w1t + (size_t)(oc0 + nt * 16 + li) * 64 + g * 16 + (j & 1) * 8;

        bf16x8 B0[4], B1[4];
#pragma unroll
        for (int nt = 0; nt < 4; ++nt) B0[nt] = *(const bf16x8*)(wl[nt]);

#pragma unroll
        for (int p = 0; p < 7; ++p) {
#pragma unroll
            for (int q = 0; q < 7; ++q) {
                const int tap = p * 7 + q;
                if (tap < 48) {   // prefetch next tap's B into the other buffer
#pragma unroll
                    for (int nt = 0; nt < 4; ++nt) {
                        bf16x8 v = *(const bf16x8*)(wl[nt] + (size_t)(tap + 1) * 8192);
                        if (((tap + 1) & 1) == 0) B0[nt] = v; else B1[nt] = v;
                    }
                }
#pragma unroll
                for (int mt = 0; mt < 7; ++mt) {
                    int site = sbase[mt] + p * 136 + 2 * q;
                    int ch   = (j ^ ((swb[mt] + q) & 3)) & 3;
                    const bf16x8 a = *(const bf16x8*)(xs + site * 32 + ch * 8);
#pragma unroll
                    for (int nt = 0; nt < 4; ++nt) {
                        const bf16x8 bb = ((tap & 1) == 0) ? B0[nt] : B1[nt];
                        acc[mt][nt] = __builtin_amdgcn_mfma_f32_16x16x32_bf16(
                            a, bb, acc[mt][nt], 0, 0, 0);
                    }
                }
            }
        }
    }

    // epilogue: D col = oc (lane&15), row = pixel (lane>>4)*4 + i -> float4 stores
    const int pixb = h0 * 56 + wm * 112 + j * 4;
#pragma unroll
    for (int nt = 0; nt < 4; ++nt) {
        int oc = oc0 + nt * 16 + li;
        float bias = b1[oc];
        float* kp = k1 + ((size_t)b * 128 + oc) * HW;
#pragma unroll
        for (int mt = 0; mt < 7; ++mt) {
            f32x4 v = acc[mt][nt];
            v[0] += bias; v[1] += bias; v[2] += bias; v[3] += bias;
            *(f32x4*)(kp + pixb + mt * 16) = v;
        }
    }
}

// ---------------- conv2 (1x1, 128->49) + softmax over 49 ----------------
__global__ __launch_bounds__(256) void conv2_softmax_kernel(
    const float* __restrict__ k1, const float* __restrict__ w2,
    const float* __restrict__ b2, float* __restrict__ attn)
{
    __shared__ float w2s[49 * 128];
    for (int i = threadIdx.x; i < 49 * 128; i += 256) w2s[i] = w2[i];
    __syncthreads();

    int gpix = blockIdx.x * 256 + threadIdx.x;
    int b = gpix / HW;
    int s = gpix - b * HW;

    float logit[49];
#pragma unroll
    for (int a = 0; a < 49; ++a) logit[a] = b2[a];

    const float* kp = k1 + (size_t)b * 128 * HW + s;
    for (int m = 0; m < 128; ++m) {
        float v = kp[(size_t)m * HW];
#pragma unroll
        for (int a = 0; a < 49; ++a)
            logit[a] = fmaf(v, w2s[a * 128 + m], logit[a]);
    }

    float mx = logit[0];
#pragma unroll
    for (int a = 1; a < 49; ++a) mx = fmaxf(mx, logit[a]);
    float sum = 0.f;
#pragma unroll
    for (int a = 0; a < 49; ++a) { logit[a] = __expf(logit[a] - mx); sum += logit[a]; }
    float inv = 1.f / sum;

    float* ap = attn + (size_t)b * (49 * HW) + s;
#pragma unroll
    for (int a = 0; a < 49; ++a) ap[(size_t)a * HW] = logit[a] * inv;
}

// ---------------- final grouped einsum ----------------
__global__ __launch_bounds__(256) void gather_kernel(
    const float* __restrict__ x, const float* __restrict__ attn,
    float* __restrict__ out)
{
    int F = blockIdx.x * 256 + threadIdx.x;
    int g = F >> 6;

    int w = F % 56;
    int t = F / 56;
    int h = t % 56;
    t /= 56;   // b*64 + c

    const float* xp = x + (size_t)t * HW;
    const float* ap = attn + (size_t)g * 49;

    float acc = 0.f;
#pragma unroll
    for (int p = 0; p < 7; ++p) {
        int hh = h + 2 * p - 6;
        bool hok = (hh >= 0) && (hh < 56);
#pragma unroll
        for (int q = 0; q < 7; ++q) {
            int ww = w + 2 * q - 6;
            float a = ap[p * 7 + q];   // wave-uniform
            float xv = 0.f;
            if (hok && ww >= 0 && ww < 56) xv = xp[hh * 56 + ww];
            acc = fmaf(xv, a, acc);
        }
    }
    out[F] = acc;
}

extern "C" void kernel_launch(void* const* d_in, const int* in_sizes, int n_in,
                              void* d_out, int out_size, void* d_ws, size_t ws_size,
                              hipStream_t stream)
{
    const float* x  = (const float*)d_in[0];
    const float* w1 = (const float*)d_in[1];
    const float* b1 = (const float*)d_in[2];
    const float* w2 = (const float*)d_in[3];
    const float* b2 = (const float*)d_in[4];
    float* out = (float*)d_out;

    float* k1   = (float*)d_ws;                       // 25.7 MB
    float* attn = k1 + K1_ELEMS;                      //  9.8 MB
    unsigned short* xg  = (unsigned short*)(attn + ATTN_ELEMS);  // 12.8 MB
    unsigned short* w1t = xg + K1_ELEMS;              //  0.8 MB

    prep_x<<<196, 256, 0, stream>>>(x, xg);
    prep_w<<<25, 256, 0, stream>>>(w1, w1t);
    conv1_mfma<<<224, 256, 0, stream>>>(xg, w1t, b1, k1);
    conv2_softmax_kernel<<<196, 256, 0, stream>>>(k1, w2, b2, attn);
    gather_kernel<<<12544, 256, 0, stream>>>(x, attn, out);
}

// Round 3
// 135.634 us; speedup vs baseline: 6.1227x; 1.6737x over previous
//
#include <hip/hip_runtime.h>
#include <hip/hip_bf16.h>

#define HW 3136            // 56*56
#define NPIX 50176         // 16*3136
#define ATTN_ELEMS 2458624 // 16*49*3136

typedef __attribute__((ext_vector_type(8))) _Float16 f16x8;
typedef __attribute__((ext_vector_type(4))) float f32x4;
typedef __attribute__((ext_vector_type(8))) unsigned short u16x8;

__device__ inline void gl_lds16(const void* g, void* l){
    __builtin_amdgcn_global_load_lds((const __attribute__((address_space(1))) void*)g,
                                     (__attribute__((address_space(3))) void*)l, 16, 0, 0);
}
__device__ inline unsigned short f2h(float v){
    _Float16 h = (_Float16)v;
    union { _Float16 h; unsigned short u; } cv; cv.h = h; return cv.u;
}
__device__ inline float h2f(unsigned short u){
    union { unsigned short u; _Float16 h; } cv; cv.u = u; return (float)cv.h;
}

// ---------- prep: x[b][ic][h][w] -> xg[(b*2+g)][h][w][32ic fp16], octet-swizzled ----------
// phys octet p holds logical octet j = p ^ ((w>>1)&3)  (proven 0-conflict scheme)
__global__ __launch_bounds__(256) void prep_x(const float* __restrict__ x,
                                              unsigned short* __restrict__ xg)
{
    int t = blockIdx.x * 256 + threadIdx.x;   // < 100352
    int g = t / NPIX;                          // 0,1 (ic half)
    int pix = t - g * NPIX;
    int b = pix / HW; int s = pix - b * HW;
    int w = s % 56;
    int key = (w >> 1) & 3;
    const float* xp = x + (size_t)b * 64 * HW + (size_t)g * 32 * HW + s;
    unsigned short* dst = xg + ((size_t)(b * 2 + g) * HW + s) * 32;
#pragma unroll
    for (int p = 0; p < 4; ++p) {
        int j = p ^ key;
        alignas(16) unsigned short tmp[8];
#pragma unroll
        for (int e = 0; e < 8; ++e)
            tmp[e] = f2h(xp[(size_t)(j * 8 + e) * HW]);
        *(u16x8*)(dst + p * 8) = *(const u16x8*)tmp;
    }
}

// ---------- prep: w1[oc][ic][p][q] -> w1t[g][tap][oc][32ic] fp16 ----------
__global__ __launch_bounds__(256) void prep_w(const float* __restrict__ w1,
                                              unsigned short* __restrict__ w1t)
{
    int t = blockIdx.x * 256 + threadIdx.x;   // < 12544
    if (t >= 2 * 49 * 128) return;
    int g = t / (49 * 128);
    int r = t - g * 49 * 128;
    int tap = r / 128; int oc = r - tap * 128;
    unsigned short* dst = w1t + (size_t)t * 32;
    for (int ic = 0; ic < 32; ++ic)
        dst[ic] = f2h(w1[((size_t)oc * 64 + g * 32 + ic) * 49 + tap]);
}

// ---------- conv1 implicit-GEMM MFMA, K-split by ic-half across blocks ----------
// grid 448 = (b16, g2, rowgrp14); block 256 thr = 4 waves (2M x 2N); wave = 7mt x 4nt
// LDS: 16 rows x 68 cols x 64B (32 ic fp16/site), single stage, halo pre-zeroed
__global__ __launch_bounds__(256, 2) void conv1_mfma(
    const unsigned short* __restrict__ xg, const unsigned short* __restrict__ w1t,
    const float* __restrict__ b1, unsigned short* __restrict__ k1a,
    unsigned short* __restrict__ k1b)
{
    __shared__ unsigned short xs[16 * 68 * 32];   // 69632 B

    const int blk = blockIdx.x;
    const int b   = blk / 28; int rem = blk - b * 28;
    const int g   = rem / 14; const int rg = rem - g * 14;
    const int h0  = rg * 4;
    const int tid = threadIdx.x;
    const int lane = tid & 63, warp = tid >> 6;
    const int wm  = warp >> 1;
    const int oc0 = (warp & 1) * 64;
    const int li  = lane & 15, j = lane >> 4;

    // zero LDS (halo stays zero)
    {
        f32x4 zv = {0.f, 0.f, 0.f, 0.f};
#pragma unroll 1
        for (int i = tid; i < 16 * 68 * 32 / 8; i += 256)
            *(f32x4*)(xs + (size_t)i * 8) = zv;
    }
    __syncthreads();

    // stage 16 rows (valid ones) of this ic-half
    {
        const unsigned short* plane = xg + (size_t)(b * 2 + g) * HW * 32;
        for (int r = warp; r < 16; r += 4) {
            int hh = h0 - 6 + r;
            if (hh >= 0 && hh < 56) {
                const unsigned short* src = plane + (size_t)hh * 56 * 32;
                char* dstb = (char*)xs + (r * 68 + 6) * 64;
#pragma unroll
                for (int kk = 0; kk < 4; ++kk) {
                    int idx = kk * 64 + lane;
                    if (idx < 224) gl_lds16(src + idx * 8, dstb + kk * 1024);
                }
            }
        }
    }
    __syncthreads();

    int abase[7], swb[7];
#pragma unroll
    for (int mt = 0; mt < 7; ++mt) {
        int local = wm * 112 + mt * 16 + li;
        int rb = local / 56; int wp = local - rb * 56;
        abase[mt] = (rb * 68 + wp) * 32;     // short index of site (p,q add later)
        swb[mt]   = (wp + 58) >> 1;          // swizzle key base
    }

    f32x4 acc[7][4];
#pragma unroll
    for (int mt = 0; mt < 7; ++mt)
#pragma unroll
        for (int nt = 0; nt < 4; ++nt)
#pragma unroll
            for (int c = 0; c < 4; ++c) acc[mt][nt][c] = 0.f;

    // per-lane B pointers (layout [g][tap][oc][32])
    const unsigned short* wln[4];
#pragma unroll
    for (int nt = 0; nt < 4; ++nt)
        wln[nt] = w1t + ((size_t)g * 49 * 128 + (size_t)(oc0 + nt * 16 + li)) * 32 + j * 8;

#pragma unroll
    for (int p = 0; p < 7; ++p) {
#pragma unroll
        for (int q = 0; q < 7; ++q) {
            const int tap = p * 7 + q;
            f16x8 Bf[4];
#pragma unroll
            for (int nt = 0; nt < 4; ++nt)
                Bf[nt] = *(const f16x8*)(wln[nt] + (size_t)tap * 4096);
#pragma unroll
            for (int mt = 0; mt < 7; ++mt) {
                int ch = (j ^ (swb[mt] + q)) & 3;
                const f16x8 a = *(const f16x8*)(xs + abase[mt] + (p * 136 + 2 * q) * 32 + ch * 8);
#pragma unroll
                for (int nt = 0; nt < 4; ++nt)
                    acc[mt][nt] = __builtin_amdgcn_mfma_f32_16x16x32_f16(
                        a, Bf[nt], acc[mt][nt], 0, 0, 0);
            }
        }
    }

    // epilogue: fp16 pixel-major partial; row = pixel = j*4+i, col = oc = li
    unsigned short* k1g = (g == 0) ? k1a : k1b;
    const int pixbase = h0 * 56 + wm * 112;
#pragma unroll
    for (int nt = 0; nt < 4; ++nt) {
        int oc = oc0 + nt * 16 + li;
        float bias = (g == 0) ? b1[oc] : 0.f;
#pragma unroll
        for (int mt = 0; mt < 7; ++mt) {
            int px0 = pixbase + mt * 16 + j * 4;
#pragma unroll
            for (int i = 0; i < 4; ++i) {
                float v = acc[mt][nt][i] + bias;
                k1g[((size_t)b * HW + px0 + i) * 128 + oc] = f2h(v);
            }
        }
    }
}

// ---------- conv2 (1x1, 128->49) + softmax; lane pairs split the m-dim ----------
__global__ __launch_bounds__(256) void conv2_softmax(
    const unsigned short* __restrict__ k1a, const unsigned short* __restrict__ k1b,
    const float* __restrict__ w2, const float* __restrict__ b2,
    float* __restrict__ attn)
{
    __shared__ float w2s[49 * 128];
    for (int i = threadIdx.x; i < 49 * 128; i += 256) w2s[i] = w2[i];
    __syncthreads();

    int t = blockIdx.x * 256 + threadIdx.x;   // < 100352
    int pix = t >> 1; int hh = t & 1;         // lane pair shares a pixel
    int b = pix / HW; int s = pix - b * HW;

    float logit[49];
#pragma unroll
    for (int a = 0; a < 49; ++a) logit[a] = hh ? 0.f : b2[a];

    const unsigned short* pa = k1a + (size_t)pix * 128 + hh * 64;
    const unsigned short* pb = k1b + (size_t)pix * 128 + hh * 64;
#pragma unroll 1
    for (int c = 0; c < 8; ++c) {
        u16x8 va = *(const u16x8*)(pa + c * 8);
        u16x8 vb = *(const u16x8*)(pb + c * 8);
#pragma unroll
        for (int e = 0; e < 8; ++e) {
            float v = h2f(va[e]) + h2f(vb[e]);
            const float* wrow = w2s + hh * 64 + c * 8 + e;
#pragma unroll
            for (int a = 0; a < 49; ++a)
                logit[a] = fmaf(v, wrow[a * 128], logit[a]);
        }
    }
#pragma unroll
    for (int a = 0; a < 49; ++a) logit[a] += __shfl_xor(logit[a], 1, 64);

    float mx = logit[0];
#pragma unroll
    for (int a = 1; a < 49; ++a) mx = fmaxf(mx, logit[a]);
    float sum = 0.f;
#pragma unroll
    for (int a = 0; a < 49; ++a) { logit[a] = __expf(logit[a] - mx); sum += logit[a]; }
    float inv = 1.f / sum;

    int a0 = hh ? 25 : 0, a1 = hh ? 49 : 25;
#pragma unroll
    for (int a = 0; a < 49; ++a)
        if (a >= a0 && a < a1)
            attn[((size_t)b * 49 + a) * HW + s] = logit[a] * inv;
}

// ---------- final grouped einsum ----------
__global__ __launch_bounds__(256) void gather_kernel(
    const float* __restrict__ x, const float* __restrict__ attn,
    float* __restrict__ out)
{
    int F = blockIdx.x * 256 + threadIdx.x;
    int g = F >> 6;
    int w = F % 56;
    int t = F / 56;
    int h = t % 56;
    t /= 56;   // b*64 + c

    const float* xp = x + (size_t)t * HW;
    const float* ap = attn + (size_t)g * 49;

    float acc = 0.f;
#pragma unroll
    for (int p = 0; p < 7; ++p) {
        int hhh = h + 2 * p - 6;
        bool hok = (hhh >= 0) && (hhh < 56);
#pragma unroll
        for (int q = 0; q < 7; ++q) {
            int ww = w + 2 * q - 6;
            float a = ap[p * 7 + q];   // wave-uniform
            float xv = 0.f;
            if (hok && ww >= 0 && ww < 56) xv = xp[hhh * 56 + ww];
            acc = fmaf(xv, a, acc);
        }
    }
    out[F] = acc;
}

extern "C" void kernel_launch(void* const* d_in, const int* in_sizes, int n_in,
                              void* d_out, int out_size, void* d_ws, size_t ws_size,
                              hipStream_t stream)
{
    const float* x  = (const float*)d_in[0];
    const float* w1 = (const float*)d_in[1];
    const float* b1 = (const float*)d_in[2];
    const float* w2 = (const float*)d_in[3];
    const float* b2 = (const float*)d_in[4];
    float* out = (float*)d_out;

    unsigned short* k1a = (unsigned short*)d_ws;          // 12.85 MB
    unsigned short* k1b = k1a + (size_t)NPIX * 128;       // 12.85 MB
    float* attn = (float*)(k1b + (size_t)NPIX * 128);     //  9.83 MB
    unsigned short* xg  = (unsigned short*)(attn + ATTN_ELEMS); // 6.42 MB
    unsigned short* w1t = xg + (size_t)16 * 2 * HW * 32;  //  0.80 MB

    prep_x<<<392, 256, 0, stream>>>(x, xg);
    prep_w<<<49, 256, 0, stream>>>(w1, w1t);
    conv1_mfma<<<448, 256, 0, stream>>>(xg, w1t, b1, k1a, k1b);
    conv2_softmax<<<392, 256, 0, stream>>>(k1a, k1b, w2, b2, attn);
    gather_kernel<<<12544, 256, 0, stream>>>(x, attn, out);
}

// Round 4
// 92.443 us; speedup vs baseline: 8.9833x; 1.4672x over previous
//
#include <hip/hip_runtime.h>
#include <hip/hip_bf16.h>

#define HW 3136            // 56*56
#define NPIX 50176         // 16*3136

typedef __attribute__((ext_vector_type(8))) _Float16 f16x8;
typedef __attribute__((ext_vector_type(4))) float f32x4;
typedef __attribute__((ext_vector_type(8))) unsigned short u16x8;

__device__ inline void gl_lds16(const void* g, void* l){
    __builtin_amdgcn_global_load_lds((const __attribute__((address_space(1))) void*)g,
                                     (__attribute__((address_space(3))) void*)l, 16, 0, 0);
}
__device__ inline unsigned short f2h(float v){
    _Float16 h = (_Float16)v;
    union { _Float16 h; unsigned short u; } cv; cv.h = h; return cv.u;
}
__device__ inline float h2f(unsigned short u){
    union { unsigned short u; _Float16 h; } cv; cv.u = u; return (float)cv.h;
}

// ================= fused prep =================
// part A (blocks 0..391):   x -> xg[(b*2+g)][s][32ic fp16], octet-swizzled (proven r2/r3)
// part B (blocks 392..663): x -> xpad[plane][68 rows][72 cols] fp16, zero halo
// part C (blocks 664..712): w1 -> w1t[g][tap][oc][32ic] fp16
__global__ __launch_bounds__(256) void prep_all(
    const float* __restrict__ x, const float* __restrict__ w1,
    unsigned short* __restrict__ xg, unsigned short* __restrict__ w1t,
    unsigned short* __restrict__ xpad)
{
    int bb = blockIdx.x;
    if (bb < 392) {
        int t = bb * 256 + threadIdx.x;           // < 100352
        int g = t / NPIX;
        int pix = t - g * NPIX;
        int b = pix / HW; int s = pix - b * HW;
        int w = s % 56;
        int key = (w >> 1) & 3;
        const float* xp = x + (size_t)b * 64 * HW + (size_t)g * 32 * HW + s;
        unsigned short* dst = xg + ((size_t)(b * 2 + g) * HW + s) * 32;
#pragma unroll
        for (int p = 0; p < 4; ++p) {
            int j = p ^ key;
            alignas(16) unsigned short tmp[8];
#pragma unroll
            for (int e = 0; e < 8; ++e)
                tmp[e] = f2h(xp[(size_t)(j * 8 + e) * HW]);
            *(u16x8*)(dst + p * 8) = *(const u16x8*)tmp;
        }
    } else if (bb < 664) {
        int t2 = (bb - 392) * 256 + threadIdx.x;  // < 69632
        int plane = t2 / 68; int r = t2 - plane * 68;
        unsigned short* dst = xpad + ((size_t)plane * 68 + r) * 72;
        int h = r - 6;
        alignas(16) unsigned short tmp[72];
#pragma unroll
        for (int i = 0; i < 72; ++i) tmp[i] = 0;
        if (h >= 0 && h < 56) {
            const float* src = x + (size_t)plane * HW + h * 56;
#pragma unroll
            for (int wq = 0; wq < 56; ++wq) tmp[6 + wq] = f2h(src[wq]);
        }
#pragma unroll
        for (int k = 0; k < 9; ++k)
            *(u16x8*)(dst + k * 8) = *(const u16x8*)(tmp + k * 8);
    } else {
        int t = (bb - 664) * 256 + threadIdx.x;   // < 12544 = 2*49*128
        int g = t / (49 * 128);
        int r = t - g * 49 * 128;
        int tap = r / 128; int oc = r - tap * 128;
        unsigned short* dst = w1t + (size_t)t * 32;
        for (int ic = 0; ic < 32; ++ic)
            dst[ic] = f2h(w1[((size_t)oc * 64 + g * 32 + ic) * 49 + tap]);
    }
}

// ================= conv1: implicit-GEMM MFMA, N-split, SW-pipelined =================
// grid 448 = (b16, nh2, rg14); block 256 = 4 waves (2 wm x 2 wn); wave = 112px x 32oc
// K = 2 ic-halves (LDS restage) x 49 taps x K32
#define LOADA(A, tap) do {                                                    \
    int p_ = ((tap) * 9363) >> 16;                                            \
    int q_ = (tap) - p_ * 7;                                                  \
    int base_ = p_ * 4352 + q_ * 64;                                          \
    _Pragma("unroll")                                                         \
    for (int mt = 0; mt < 7; ++mt) {                                          \
        int ch_ = (j ^ (swb[mt] + q_)) & 3;                                   \
        A[mt] = *(const f16x8*)(xs + abase[mt] + base_ + ch_ * 8);            \
    } } while(0)

#define LOADB(Bf, tap) do {                                                   \
    int tp_ = (tap) > 48 ? 48 : (tap);                                        \
    size_t o_ = (size_t)tp_ * 4096;                                           \
    Bf[0] = *(const f16x8*)(wl0 + o_);                                        \
    Bf[1] = *(const f16x8*)(wl1 + o_); } while(0)

#define DOMFMA(A, Bf) do {                                                    \
    _Pragma("unroll")                                                         \
    for (int mt = 0; mt < 7; ++mt) {                                          \
        acc[mt][0] = __builtin_amdgcn_mfma_f32_16x16x32_f16(A[mt], Bf[0], acc[mt][0], 0, 0, 0); \
        acc[mt][1] = __builtin_amdgcn_mfma_f32_16x16x32_f16(A[mt], Bf[1], acc[mt][1], 0, 0, 0); \
    } } while(0)

__global__ __launch_bounds__(256, 2) void conv1_mfma(
    const unsigned short* __restrict__ xg, const unsigned short* __restrict__ w1t,
    const float* __restrict__ b1, unsigned short* __restrict__ k1)
{
    __shared__ unsigned short xs[16 * 68 * 32];   // 69632 B

    const int blk = blockIdx.x;
    const int b   = blk / 28; int rem = blk - b * 28;
    const int nh  = rem / 14; const int rg = rem - nh * 14;
    const int h0  = rg * 4;
    const int tid = threadIdx.x;
    const int lane = tid & 63, warp = tid >> 6;
    const int wm  = warp >> 1;
    const int oc0 = nh * 64 + (warp & 1) * 32;
    const int li  = lane & 15, j = lane >> 4;

    // zero LDS (halo stays zero across both stages)
    {
        f32x4 zv = {0.f, 0.f, 0.f, 0.f};
#pragma unroll 1
        for (int i = tid; i < 16 * 68 * 32 / 8; i += 256)
            *(f32x4*)(xs + (size_t)i * 8) = zv;
    }

    int abase[7], swb[7];
#pragma unroll
    for (int mt = 0; mt < 7; ++mt) {
        int local = wm * 112 + mt * 16 + li;
        int rb = local / 56; int wp = local - rb * 56;
        abase[mt] = (rb * 68 + wp) * 32;
        swb[mt]   = (wp + 58) >> 1;
    }

    f32x4 acc[7][2];
#pragma unroll
    for (int mt = 0; mt < 7; ++mt)
#pragma unroll
        for (int nt = 0; nt < 2; ++nt)
#pragma unroll
            for (int c = 0; c < 4; ++c) acc[mt][nt][c] = 0.f;

#pragma unroll 1
    for (int g = 0; g < 2; ++g) {
        __syncthreads();   // prior readers done (covers zero-init on g=0)
        {
            const unsigned short* plane = xg + (size_t)(b * 2 + g) * HW * 32;
            for (int r = warp; r < 16; r += 4) {
                int hh = h0 - 6 + r;
                if (hh >= 0 && hh < 56) {
                    const unsigned short* src = plane + (size_t)hh * 56 * 32;
                    char* dstb = (char*)xs + (r * 68 + 6) * 64;
#pragma unroll
                    for (int kk = 0; kk < 4; ++kk) {
                        int idx = kk * 64 + lane;
                        if (idx < 224) gl_lds16(src + idx * 8, dstb + kk * 1024);
                    }
                }
            }
        }
        __syncthreads();

        const unsigned short* wl0 = w1t + ((size_t)g * 49 * 128 + (oc0 + li)) * 32 + j * 8;
        const unsigned short* wl1 = wl0 + 16 * 32;

        f16x8 Ac[7], An[7], Be[2], Bo[2];
        LOADA(Ac, 0); LOADB(Be, 0); LOADB(Bo, 1);
#pragma unroll 1
        for (int t = 0; t < 24; ++t) {
            LOADA(An, 2 * t + 1);
            DOMFMA(Ac, Be);                // tap 2t
            LOADB(Be, 2 * t + 2);
            LOADA(Ac, 2 * t + 2);
            DOMFMA(An, Bo);                // tap 2t+1
            LOADB(Bo, 2 * t + 3);
        }
        DOMFMA(Ac, Be);                    // tap 48
    }

    // epilogue: k1 pixel-major fp16, full bias (single final buffer)
    const int pixbase = h0 * 56 + wm * 112;
#pragma unroll
    for (int nt = 0; nt < 2; ++nt) {
        int oc = oc0 + nt * 16 + li;
        float bias = b1[oc];
#pragma unroll
        for (int mt = 0; mt < 7; ++mt) {
#pragma unroll
            for (int i = 0; i < 4; ++i) {
                int pix = pixbase + mt * 16 + j * 4 + i;
                k1[((size_t)b * HW + pix) * 128 + oc] = f2h(acc[mt][nt][i] + bias);
            }
        }
    }
}

// ================= conv2 (1x1, 128->49) as MFMA + fused softmax =================
// D rows = taps (64 padded), cols = pixels; wave = one 16-px tile; grid 784 x 4 waves
__global__ __launch_bounds__(256) void conv2_mfma(
    const unsigned short* __restrict__ k1, const float* __restrict__ w2,
    const float* __restrict__ b2, float* __restrict__ attn)
{
    __shared__ unsigned short w2s[64 * 128];   // 16 KB, octet-XOR-swizzled by row&7
    int tid = threadIdx.x;
    for (int u = tid; u < 1024; u += 256) {
        int r = u >> 4, o = u & 15;
        alignas(16) unsigned short tmp[8];
#pragma unroll
        for (int e = 0; e < 8; ++e)
            tmp[e] = (r < 49) ? f2h(w2[r * 128 + o * 8 + e]) : (unsigned short)0;
        *(u16x8*)(w2s + r * 128 + ((o ^ (r & 7)) * 8)) = *(const u16x8*)tmp;
    }
    __syncthreads();

    int lane = tid & 63, wid = tid >> 6;
    int li = lane & 15, j = lane >> 4;
    int pxb = blockIdx.x * 64 + wid * 16;

    float bias[16];
#pragma unroll
    for (int nt = 0; nt < 4; ++nt)
#pragma unroll
        for (int i = 0; i < 4; ++i) {
            int r = nt * 16 + j * 4 + i;
            bias[nt * 4 + i] = (r < 49) ? b2[r] : 0.f;
        }

    const unsigned short* kp = k1 + (size_t)(pxb + li) * 128;
    f32x4 acc[4];
#pragma unroll
    for (int nt = 0; nt < 4; ++nt)
#pragma unroll
        for (int c = 0; c < 4; ++c) acc[nt][c] = 0.f;

#pragma unroll
    for (int ks = 0; ks < 4; ++ks) {
        f16x8 bf = *(const f16x8*)(kp + ks * 32 + j * 8);
#pragma unroll
        for (int nt = 0; nt < 4; ++nt) {
            int r = nt * 16 + li;
            const f16x8 af = *(const f16x8*)(w2s + r * 128 + (((ks * 4 + j) ^ (li & 7)) * 8));
            acc[nt] = __builtin_amdgcn_mfma_f32_16x16x32_f16(af, bf, acc[nt], 0, 0, 0);
        }
    }

    // softmax over rows 0..48 (rows spread across j-groups; cols = pixels = li)
    float mx = -3e38f;
#pragma unroll
    for (int nt = 0; nt < 4; ++nt)
#pragma unroll
        for (int i = 0; i < 4; ++i) {
            int r = nt * 16 + j * 4 + i;
            float v = acc[nt][i] + bias[nt * 4 + i];
            acc[nt][i] = v;
            if (r < 49) mx = fmaxf(mx, v);
        }
    mx = fmaxf(mx, __shfl_xor(mx, 16));
    mx = fmaxf(mx, __shfl_xor(mx, 32));

    float sum = 0.f; float ex[16];
#pragma unroll
    for (int nt = 0; nt < 4; ++nt)
#pragma unroll
        for (int i = 0; i < 4; ++i) {
            int r = nt * 16 + j * 4 + i;
            float e = (r < 49) ? __expf(acc[nt][i] - mx) : 0.f;
            ex[nt * 4 + i] = e; sum += e;
        }
    sum += __shfl_xor(sum, 16);
    sum += __shfl_xor(sum, 32);
    float inv = 1.f / sum;

    int pix = pxb + li; int b = pix / HW; int s = pix - b * HW;
    float* apx = attn + (size_t)b * 49 * HW + s;
#pragma unroll
    for (int nt = 0; nt < 4; ++nt)
#pragma unroll
        for (int i = 0; i < 4; ++i) {
            int r = nt * 16 + j * 4 + i;
            if (r < 49) apx[(size_t)r * HW] = ex[nt * 4 + i] * inv;
        }
}

// ================= final grouped einsum, 8 outputs/thread from padded fp16 x =================
__global__ __launch_bounds__(256) void gather_kernel(
    const unsigned short* __restrict__ xpad, const float* __restrict__ attn,
    float* __restrict__ out)
{
    int tid = blockIdx.x * 256 + threadIdx.x;   // < 401408
    int plane = tid / 392;                      // b*64 + c
    int r1 = tid - plane * 392;
    int h = r1 / 7; int oct = r1 - h * 7; int w0 = oct * 8;
    int F0 = plane * HW + h * 56 + w0;

    const float* ap = attn + (size_t)(F0 >> 6) * 49;
    float a[49];
#pragma unroll
    for (int k = 0; k < 49; ++k) a[k] = ap[k];

    const unsigned short* xp = xpad + (size_t)plane * (68 * 72) + w0;
    float o[8];
#pragma unroll
    for (int dw = 0; dw < 8; ++dw) o[dw] = 0.f;

#pragma unroll
    for (int p = 0; p < 7; ++p) {
        const unsigned short* rp = xp + (h + 2 * p) * 72;
        u16x8 v0 = *(const u16x8*)rp;
        u16x8 v1 = *(const u16x8*)(rp + 8);
        u16x8 v2 = *(const u16x8*)(rp + 16);
        float rr[20];
#pragma unroll
        for (int e = 0; e < 8; ++e) { rr[e] = h2f(v0[e]); rr[8 + e] = h2f(v1[e]); }
#pragma unroll
        for (int e = 0; e < 4; ++e) rr[16 + e] = h2f(v2[e]);
#pragma unroll
        for (int q = 0; q < 7; ++q) {
            float aq = a[p * 7 + q];
#pragma unroll
            for (int dw = 0; dw < 8; ++dw)
                o[dw] = fmaf(rr[dw + 2 * q], aq, o[dw]);
        }
    }

    f32x4 s0 = {o[0], o[1], o[2], o[3]};
    f32x4 s1 = {o[4], o[5], o[6], o[7]};
    *(f32x4*)(out + F0) = s0;
    *(f32x4*)(out + F0 + 4) = s1;
}

extern "C" void kernel_launch(void* const* d_in, const int* in_sizes, int n_in,
                              void* d_out, int out_size, void* d_ws, size_t ws_size,
                              hipStream_t stream)
{
    const float* x  = (const float*)d_in[0];
    const float* w1 = (const float*)d_in[1];
    const float* b1 = (const float*)d_in[2];
    const float* w2 = (const float*)d_in[3];
    const float* b2 = (const float*)d_in[4];
    float* out = (float*)d_out;

    unsigned short* k1  = (unsigned short*)d_ws;           // 12.85 MB
    float* attn = (float*)(k1 + (size_t)NPIX * 128);       //  9.83 MB
    unsigned short* xg  = (unsigned short*)(attn + (size_t)16 * 49 * HW);  // 6.42 MB
    unsigned short* w1t = xg + (size_t)16 * 2 * HW * 32;   //  0.80 MB
    unsigned short* xpad = w1t + (size_t)2 * 49 * 128 * 32; // 10.03 MB  (total ~40 MB)

    prep_all<<<713, 256, 0, stream>>>(x, w1, xg, w1t, xpad);
    conv1_mfma<<<448, 256, 0, stream>>>(xg, w1t, b1, k1);
    conv2_mfma<<<784, 256, 0, stream>>>(k1, w2, b2, attn);
    gather_kernel<<<1568, 256, 0, stream>>>(xpad, attn, out);
}

// Round 5
// 90.958 us; speedup vs baseline: 9.1299x; 1.0163x over previous
//
#include <hip/hip_runtime.h>
#include <hip/hip_bf16.h>

#define HW 3136            // 56*56
#define NPIX 50176         // 16*3136

typedef __attribute__((ext_vector_type(8))) _Float16 f16x8;
typedef __attribute__((ext_vector_type(4))) float f32x4;
typedef __attribute__((ext_vector_type(8))) unsigned short u16x8;

__device__ inline void gl_lds16(const void* g, void* l){
    __builtin_amdgcn_global_load_lds((const __attribute__((address_space(1))) void*)g,
                                     (__attribute__((address_space(3))) void*)l, 16, 0, 0);
}
__device__ inline unsigned short f2h(float v){
    _Float16 h = (_Float16)v;
    union { _Float16 h; unsigned short u; } cv; cv.h = h; return cv.u;
}
__device__ inline float h2f(unsigned short u){
    union { unsigned short u; _Float16 h; } cv; cv.u = u; return (float)cv.h;
}

// ================= fused prep (unchanged, r4-proven) =================
__global__ __launch_bounds__(256) void prep_all(
    const float* __restrict__ x, const float* __restrict__ w1,
    unsigned short* __restrict__ xg, unsigned short* __restrict__ w1t,
    unsigned short* __restrict__ xpad)
{
    int bb = blockIdx.x;
    if (bb < 392) {
        int t = bb * 256 + threadIdx.x;           // < 100352
        int g = t / NPIX;
        int pix = t - g * NPIX;
        int b = pix / HW; int s = pix - b * HW;
        int w = s % 56;
        int key = (w >> 1) & 3;
        const float* xp = x + (size_t)b * 64 * HW + (size_t)g * 32 * HW + s;
        unsigned short* dst = xg + ((size_t)(b * 2 + g) * HW + s) * 32;
#pragma unroll
        for (int p = 0; p < 4; ++p) {
            int j = p ^ key;
            alignas(16) unsigned short tmp[8];
#pragma unroll
            for (int e = 0; e < 8; ++e)
                tmp[e] = f2h(xp[(size_t)(j * 8 + e) * HW]);
            *(u16x8*)(dst + p * 8) = *(const u16x8*)tmp;
        }
    } else if (bb < 664) {
        int t2 = (bb - 392) * 256 + threadIdx.x;  // < 69632
        int plane = t2 / 68; int r = t2 - plane * 68;
        unsigned short* dst = xpad + ((size_t)plane * 68 + r) * 72;
        int h = r - 6;
        alignas(16) unsigned short tmp[72];
#pragma unroll
        for (int i = 0; i < 72; ++i) tmp[i] = 0;
        if (h >= 0 && h < 56) {
            const float* src = x + (size_t)plane * HW + h * 56;
#pragma unroll
            for (int wq = 0; wq < 56; ++wq) tmp[6 + wq] = f2h(src[wq]);
        }
#pragma unroll
        for (int k = 0; k < 9; ++k)
            *(u16x8*)(dst + k * 8) = *(const u16x8*)(tmp + k * 8);
    } else {
        int t = (bb - 664) * 256 + threadIdx.x;   // < 12544 = 2*49*128
        int g = t / (49 * 128);
        int r = t - g * 49 * 128;
        int tap = r / 128; int oc = r - tap * 128;
        unsigned short* dst = w1t + (size_t)t * 32;
        for (int ic = 0; ic < 32; ++ic)
            dst[ic] = f2h(w1[((size_t)oc * 64 + g * 32 + ic) * 49 + tap]);
    }
}

// ================= conv1: 8-row tile, 8 waves, K-split g, nt=4 =================
// grid 224 = (b16, g2, rg7); block 512 = 8 waves (4 wm x 2 wn); wave = 112px x 64oc
#define LOADA(A, tap) do {                                                    \
    int p_ = ((tap) * 9363) >> 16;                                            \
    int q_ = (tap) - p_ * 7;                                                  \
    int base_ = p_ * 4352 + q_ * 64;                                          \
    _Pragma("unroll")                                                         \
    for (int mt = 0; mt < 7; ++mt) {                                          \
        int ch_ = (j ^ (swb[mt] + q_)) & 3;                                   \
        A[mt] = *(const f16x8*)(xs + abase[mt] + base_ + ch_ * 8);            \
    } } while(0)

#define LOADB(B0, B1, B2, B3, tap) do {                                       \
    int tp_ = (tap) > 48 ? 48 : (tap);                                        \
    size_t o_ = (size_t)tp_ * 4096;                                           \
    B0 = *(const f16x8*)(wl0 + o_);                                           \
    B1 = *(const f16x8*)(wl1 + o_);                                           \
    B2 = *(const f16x8*)(wl2 + o_);                                           \
    B3 = *(const f16x8*)(wl3 + o_); } while(0)

#define DOMFMA(A, B0, B1, B2, B3) do {                                        \
    _Pragma("unroll")                                                         \
    for (int mt = 0; mt < 7; ++mt) {                                          \
        acc[mt][0] = __builtin_amdgcn_mfma_f32_16x16x32_f16(A[mt], B0, acc[mt][0], 0, 0, 0); \
        acc[mt][1] = __builtin_amdgcn_mfma_f32_16x16x32_f16(A[mt], B1, acc[mt][1], 0, 0, 0); \
        acc[mt][2] = __builtin_amdgcn_mfma_f32_16x16x32_f16(A[mt], B2, acc[mt][2], 0, 0, 0); \
        acc[mt][3] = __builtin_amdgcn_mfma_f32_16x16x32_f16(A[mt], B3, acc[mt][3], 0, 0, 0); \
    } } while(0)

__global__ __launch_bounds__(512, 2) void conv1_mfma(
    const unsigned short* __restrict__ xg, const unsigned short* __restrict__ w1t,
    const float* __restrict__ b1, unsigned short* __restrict__ k1a,
    unsigned short* __restrict__ k1b)
{
    __shared__ unsigned short xs[20 * 68 * 32];   // 87040 B -> 1 block/CU, 8 waves

    const int blk = blockIdx.x;
    const int b   = blk / 14; int rem = blk - b * 14;
    const int g   = rem / 7;  const int rg = rem - g * 7;
    const int h0  = rg * 8;
    const int tid = threadIdx.x;
    const int lane = tid & 63, warp = tid >> 6;   // 0..7
    const int wm  = warp >> 1;                    // 0..3
    const int oc0 = (warp & 1) * 64;
    const int li  = lane & 15, j = lane >> 4;

    // zero LDS (halo rows/cols stay zero)
    {
        f32x4 zv = {0.f, 0.f, 0.f, 0.f};
#pragma unroll 1
        for (int i = tid; i < 20 * 68 * 32 / 8; i += 512)
            *(f32x4*)(xs + (size_t)i * 8) = zv;
    }
    __syncthreads();   // zeros visible before gl_lds overwrites valid rows

    // stage 20 rows of this (b,g) plane
    {
        const unsigned short* plane = xg + (size_t)(b * 2 + g) * HW * 32;
        for (int r = warp; r < 20; r += 8) {
            int hh = h0 - 6 + r;
            if (hh >= 0 && hh < 56) {
                const unsigned short* src = plane + (size_t)hh * 56 * 32;
                char* dstb = (char*)xs + (r * 68 + 6) * 64;
#pragma unroll
                for (int kk = 0; kk < 4; ++kk) {
                    int idx = kk * 64 + lane;
                    if (idx < 224) gl_lds16(src + idx * 8, dstb + kk * 1024);
                }
            }
        }
    }
    __syncthreads();

    int abase[7], swb[7];
#pragma unroll
    for (int mt = 0; mt < 7; ++mt) {
        int local = wm * 112 + mt * 16 + li;      // 0..447
        int rb = local / 56; int wp = local - rb * 56;
        abase[mt] = (rb * 68 + wp) * 32;
        swb[mt]   = (wp + 58) >> 1;
    }

    f32x4 acc[7][4];
#pragma unroll
    for (int mt = 0; mt < 7; ++mt)
#pragma unroll
        for (int nt = 0; nt < 4; ++nt)
#pragma unroll
            for (int c = 0; c < 4; ++c) acc[mt][nt][c] = 0.f;

    const unsigned short* wl0 = w1t + ((size_t)g * 49 * 128 + (oc0 + li)) * 32 + j * 8;
    const unsigned short* wl1 = wl0 + 16 * 32;
    const unsigned short* wl2 = wl0 + 32 * 32;
    const unsigned short* wl3 = wl0 + 48 * 32;

    f16x8 Ac[7], An[7], Be0, Be1, Be2, Be3, Bo0, Bo1, Bo2, Bo3;
    LOADA(Ac, 0); LOADB(Be0, Be1, Be2, Be3, 0); LOADB(Bo0, Bo1, Bo2, Bo3, 1);
#pragma unroll 1
    for (int t = 0; t < 24; ++t) {
        LOADA(An, 2 * t + 1);
        DOMFMA(Ac, Be0, Be1, Be2, Be3);               // tap 2t
        LOADB(Be0, Be1, Be2, Be3, 2 * t + 2);
        LOADA(Ac, 2 * t + 2);
        DOMFMA(An, Bo0, Bo1, Bo2, Bo3);               // tap 2t+1
        LOADB(Bo0, Bo1, Bo2, Bo3, 2 * t + 3);
    }
    DOMFMA(Ac, Be0, Be1, Be2, Be3);                   // tap 48

    // epilogue: pixel-major fp16 partial (g=0 -> k1a with bias, g=1 -> k1b)
    unsigned short* k1g = (g == 0) ? k1a : k1b;
    const int pixbase = h0 * 56 + wm * 112;
#pragma unroll
    for (int nt = 0; nt < 4; ++nt) {
        int oc = oc0 + nt * 16 + li;
        float bias = (g == 0) ? b1[oc] : 0.f;
#pragma unroll
        for (int mt = 0; mt < 7; ++mt) {
#pragma unroll
            for (int i = 0; i < 4; ++i) {
                int pix = pixbase + mt * 16 + j * 4 + i;
                k1g[((size_t)b * HW + pix) * 128 + oc] = f2h(acc[mt][nt][i] + bias);
            }
        }
    }
}

// ================= conv2 (1x1, 128->49) MFMA + softmax, dual-partial combine =================
__global__ __launch_bounds__(256) void conv2_mfma(
    const unsigned short* __restrict__ k1a, const unsigned short* __restrict__ k1b,
    const float* __restrict__ w2, const float* __restrict__ b2,
    unsigned short* __restrict__ attn)
{
    __shared__ unsigned short w2s[64 * 128];   // 16 KB, octet-XOR-swizzled by row&7
    int tid = threadIdx.x;
    for (int u = tid; u < 1024; u += 256) {
        int r = u >> 4, o = u & 15;
        alignas(16) unsigned short tmp[8];
#pragma unroll
        for (int e = 0; e < 8; ++e)
            tmp[e] = (r < 49) ? f2h(w2[r * 128 + o * 8 + e]) : (unsigned short)0;
        *(u16x8*)(w2s + r * 128 + ((o ^ (r & 7)) * 8)) = *(const u16x8*)tmp;
    }
    __syncthreads();

    int lane = tid & 63, wid = tid >> 6;
    int li = lane & 15, j = lane >> 4;
    int pxb = blockIdx.x * 64 + wid * 16;

    float bias[16];
#pragma unroll
    for (int nt = 0; nt < 4; ++nt)
#pragma unroll
        for (int i = 0; i < 4; ++i) {
            int r = nt * 16 + j * 4 + i;
            bias[nt * 4 + i] = (r < 49) ? b2[r] : 0.f;
        }

    const unsigned short* kpa = k1a + (size_t)(pxb + li) * 128;
    const unsigned short* kpb = k1b + (size_t)(pxb + li) * 128;
    f32x4 acc[4];
#pragma unroll
    for (int nt = 0; nt < 4; ++nt)
#pragma unroll
        for (int c = 0; c < 4; ++c) acc[nt][c] = 0.f;

#pragma unroll
    for (int ks = 0; ks < 4; ++ks) {
        f16x8 bfa = *(const f16x8*)(kpa + ks * 32 + j * 8);
        f16x8 bfb = *(const f16x8*)(kpb + ks * 32 + j * 8);
        f16x8 bf = bfa + bfb;
#pragma unroll
        for (int nt = 0; nt < 4; ++nt) {
            int r = nt * 16 + li;
            const f16x8 af = *(const f16x8*)(w2s + r * 128 + (((ks * 4 + j) ^ (li & 7)) * 8));
            acc[nt] = __builtin_amdgcn_mfma_f32_16x16x32_f16(af, bf, acc[nt], 0, 0, 0);
        }
    }

    float mx = -3e38f;
#pragma unroll
    for (int nt = 0; nt < 4; ++nt)
#pragma unroll
        for (int i = 0; i < 4; ++i) {
            int r = nt * 16 + j * 4 + i;
            float v = acc[nt][i] + bias[nt * 4 + i];
            acc[nt][i] = v;
            if (r < 49) mx = fmaxf(mx, v);
        }
    mx = fmaxf(mx, __shfl_xor(mx, 16));
    mx = fmaxf(mx, __shfl_xor(mx, 32));

    float sum = 0.f; float ex[16];
#pragma unroll
    for (int nt = 0; nt < 4; ++nt)
#pragma unroll
        for (int i = 0; i < 4; ++i) {
            int r = nt * 16 + j * 4 + i;
            float e = (r < 49) ? __expf(acc[nt][i] - mx) : 0.f;
            ex[nt * 4 + i] = e; sum += e;
        }
    sum += __shfl_xor(sum, 16);
    sum += __shfl_xor(sum, 32);
    float inv = 1.f / sum;

    int pix = pxb + li; int b = pix / HW; int s = pix - b * HW;
    unsigned short* apx = attn + (size_t)b * 49 * HW + s;
#pragma unroll
    for (int nt = 0; nt < 4; ++nt)
#pragma unroll
        for (int i = 0; i < 4; ++i) {
            int r = nt * 16 + j * 4 + i;
            if (r < 49) apx[(size_t)r * HW] = f2h(ex[nt * 4 + i] * inv);
        }
}

// ================= final grouped einsum, 8 outputs/thread =================
__global__ __launch_bounds__(256) void gather_kernel(
    const unsigned short* __restrict__ xpad, const unsigned short* __restrict__ attn,
    float* __restrict__ out)
{
    int tid = blockIdx.x * 256 + threadIdx.x;   // < 401408
    int plane = tid / 392;                      // b*64 + c
    int r1 = tid - plane * 392;
    int h = r1 / 7; int oct = r1 - h * 7; int w0 = oct * 8;
    int F0 = plane * HW + h * 56 + w0;

    const unsigned short* ap = attn + (size_t)(F0 >> 6) * 49;
    float a[49];
#pragma unroll
    for (int k = 0; k < 49; ++k) a[k] = h2f(ap[k]);

    const unsigned short* xp = xpad + (size_t)plane * (68 * 72) + w0;
    float o[8];
#pragma unroll
    for (int dw = 0; dw < 8; ++dw) o[dw] = 0.f;

#pragma unroll
    for (int p = 0; p < 7; ++p) {
        const unsigned short* rp = xp + (h + 2 * p) * 72;
        u16x8 v0 = *(const u16x8*)rp;
        u16x8 v1 = *(const u16x8*)(rp + 8);
        u16x8 v2 = *(const u16x8*)(rp + 16);
        float rr[20];
#pragma unroll
        for (int e = 0; e < 8; ++e) { rr[e] = h2f(v0[e]); rr[8 + e] = h2f(v1[e]); }
#pragma unroll
        for (int e = 0; e < 4; ++e) rr[16 + e] = h2f(v2[e]);
#pragma unroll
        for (int q = 0; q < 7; ++q) {
            float aq = a[p * 7 + q];
#pragma unroll
            for (int dw = 0; dw < 8; ++dw)
                o[dw] = fmaf(rr[dw + 2 * q], aq, o[dw]);
        }
    }

    f32x4 s0 = {o[0], o[1], o[2], o[3]};
    f32x4 s1 = {o[4], o[5], o[6], o[7]};
    *(f32x4*)(out + F0) = s0;
    *(f32x4*)(out + F0 + 4) = s1;
}

extern "C" void kernel_launch(void* const* d_in, const int* in_sizes, int n_in,
                              void* d_out, int out_size, void* d_ws, size_t ws_size,
                              hipStream_t stream)
{
    const float* x  = (const float*)d_in[0];
    const float* w1 = (const float*)d_in[1];
    const float* b1 = (const float*)d_in[2];
    const float* w2 = (const float*)d_in[3];
    const float* b2 = (const float*)d_in[4];
    float* out = (float*)d_out;

    unsigned short* k1a  = (unsigned short*)d_ws;              // 12.85 MB
    unsigned short* k1b  = k1a + (size_t)NPIX * 128;           // 12.85 MB
    unsigned short* attn = k1b + (size_t)NPIX * 128;           //  4.92 MB (fp16)
    unsigned short* xg   = attn + (size_t)16 * 49 * HW;        //  6.42 MB
    unsigned short* w1t  = xg + (size_t)16 * 2 * HW * 32;      //  0.80 MB
    unsigned short* xpad = w1t + (size_t)2 * 49 * 128 * 32;    // 10.03 MB  (total ~47.9 MB)

    prep_all<<<713, 256, 0, stream>>>(x, w1, xg, w1t, xpad);
    conv1_mfma<<<224, 512, 0, stream>>>(xg, w1t, b1, k1a, k1b);
    conv2_mfma<<<784, 256, 0, stream>>>(k1a, k1b, w2, b2, attn);
    gather_kernel<<<1568, 256, 0, stream>>>(xpad, attn, out);
}